// Round 1
// baseline (1568.491 us; speedup 1.0000x reference)
//
#include <hip/hip_runtime.h>
#include <hip/hip_bf16.h>

#define DEV_INLINE __device__ __forceinline__

constexpr int N_NODES = 8192;
constexpr int F = 64;
constexpr int H = 128;
constexpr int G = 128;
constexpr int E_EDGES = 262144;

// ---------------------------------------------------------------------------
// Fused conv stack + pool + encoder. One block per node, 256 threads.
// Lanes index the position axis -> weight indices are wave-uniform (s_load),
// input windows live in registers -> FMA-bound.
// ---------------------------------------------------------------------------
template<int CIN, int PIN, int POUT, int KS, int PAD>
DEV_INLINE void conv_layer(const float* __restrict__ wg, const float* __restrict__ bg,
                           const float* in, float* out, int tid) {
  const int lane = tid & 63;
  const int wv = __builtin_amdgcn_readfirstlane(tid >> 6);  // 0..3, uniform
  constexpr int Q    = (POUT < 64) ? POUT : 64;   // lanes used for positions
  constexpr int NQ   = (POUT + 63) / 64;          // positions per lane
  constexpr int OSUB = 64 / Q;                    // o-splits within a wave
  constexpr int TO   = 16 / OSUB;                 // o's per lane
  const int q0 = lane % Q;
  const int os = lane / Q;
  const int obase = wv * 16 + os * TO;

  float acc[TO][NQ];
#pragma unroll
  for (int i = 0; i < TO; i++)
#pragma unroll
    for (int qq = 0; qq < NQ; qq++) acc[i][qq] = 0.f;

  for (int c = 0; c < CIN; c++) {
    float win[NQ][KS];
#pragma unroll
    for (int qq = 0; qq < NQ; qq++) {
#pragma unroll
      for (int k = 0; k < KS; k++) {
        int idx = 2 * (q0 + qq * 64) + k - PAD;
        win[qq][k] = ((unsigned)idx < (unsigned)PIN) ? in[c * PIN + idx] : 0.f;
      }
    }
#pragma unroll
    for (int i = 0; i < TO; i++) {
      const int o = obase + i;
      const float* wp = wg + (o * CIN + c) * KS;
#pragma unroll
      for (int k = 0; k < KS; k++) {
        float wk = wp[k];
#pragma unroll
        for (int qq = 0; qq < NQ; qq++) acc[i][qq] += wk * win[qq][k];
      }
    }
  }
#pragma unroll
  for (int i = 0; i < TO; i++) {
    const int o = obase + i;
    float bb = bg[o];
#pragma unroll
    for (int qq = 0; qq < NQ; qq++)
      out[o * POUT + q0 + qq * 64] = fmaxf(acc[i][qq] + bb, 0.f);
  }
}

__global__ __launch_bounds__(256) void conv_encode_kernel(
    const float* __restrict__ x,
    const float* __restrict__ cw0, const float* __restrict__ cb0,
    const float* __restrict__ cw_mid, const float* __restrict__ cb_mid,
    const float* __restrict__ cw_last, const float* __restrict__ cb_last,
    const float* __restrict__ enc_w, const float* __restrict__ enc_b,
    float* __restrict__ henc) {
  __shared__ float xs[256];
  __shared__ float bufA[64 * 128];
  __shared__ float bufB[64 * 64];
  const int n = blockIdx.x;
  const int tid = threadIdx.x;

  xs[tid] = x[n * 256 + tid];
  __syncthreads();

  conv_layer<1, 256, 128, 7, 3>(cw0, cb0, xs, bufA, tid);
  __syncthreads();
  conv_layer<64, 128, 64, 5, 2>(cw_mid, cb_mid, bufA, bufB, tid);
  __syncthreads();
  conv_layer<64, 64, 32, 5, 2>(cw_mid + 64 * 64 * 5, cb_mid + 64, bufB, bufA, tid);
  __syncthreads();
  conv_layer<64, 32, 16, 5, 2>(cw_mid + 2 * 64 * 64 * 5, cb_mid + 128, bufA, bufB, tid);
  __syncthreads();
  conv_layer<64, 16, 8, 3, 1>(cw_last, cb_last, bufB, bufA, tid);
  __syncthreads();

  // avg-pool window3 stride2 pad1 over length 8 -> 4; reshape (c,q)->j=c*4+q
  {
    int c = tid >> 2, qq = tid & 3;
    float v = bufA[c * 8 + 2 * qq] + bufA[c * 8 + 2 * qq + 1];
    if (qq > 0) v += bufA[c * 8 + 2 * qq - 1];
    xs[tid] = v / 3.0f;
  }
  __syncthreads();

  // encoder: henc[n][o] = sum_j xs[j]*enc_w[o*256+j] + enc_b[o]   (no relu)
  {
    int o = tid & 63, jg = tid >> 6;
    float a = 0.f;
    for (int jj = 0; jj < 64; jj++) {
      int j = jg * 64 + jj;
      a += xs[j] * enc_w[o * 256 + j];
    }
    bufB[jg * 64 + o] = a;
  }
  __syncthreads();
  if (tid < 64)
    henc[n * 64 + tid] = bufB[tid] + bufB[64 + tid] + bufB[128 + tid] + bufB[192 + tid] + enc_b[tid];
}

// ---------------------------------------------------------------------------
// CSR build: histogram -> scan -> fill
// ---------------------------------------------------------------------------
__global__ void hist_kernel(const int* __restrict__ dst, int* __restrict__ cnt) {
  int e = blockIdx.x * 256 + threadIdx.x;
  atomicAdd(&cnt[dst[e]], 1);
}

__global__ void scan_kernel(const int* __restrict__ cnt, int* __restrict__ rp) {
  __shared__ int part[256];
  int t = threadIdx.x;
  int base = t * 32;
  int local[32];
  int s = 0;
#pragma unroll
  for (int i = 0; i < 32; i++) { local[i] = cnt[base + i]; s += local[i]; }
  part[t] = s;
  __syncthreads();
  for (int off = 1; off < 256; off <<= 1) {
    int v = (t >= off) ? part[t - off] : 0;
    __syncthreads();
    part[t] += v;
    __syncthreads();
  }
  int run = part[t] - s;  // exclusive prefix of this thread's chunk
#pragma unroll
  for (int i = 0; i < 32; i++) { rp[base + i] = run; run += local[i]; }
  if (t == 255) rp[N_NODES] = run;
}

__global__ void fill_kernel(const int* __restrict__ src, const int* __restrict__ dst,
                            const int* __restrict__ rp, int* __restrict__ cur,
                            int* __restrict__ csr) {
  int e = blockIdx.x * 256 + threadIdx.x;
  int r = dst[e];
  int p = atomicAdd(&cur[r], 1);
  csr[rp[r] + p] = src[e];
}

// gather-based segment_sum: agg[n][t] = sum_{neighbors m} h[m][t]
__global__ void gather_kernel(const float* __restrict__ h, const int* __restrict__ csr,
                              const int* __restrict__ rp, float* __restrict__ agg, int D) {
  int n = blockIdx.x;
  int t = threadIdx.x;
  int s = rp[n], e = rp[n + 1];
  float a = 0.f;
  for (int i = s; i < e; i++) a += h[csr[i] * D + t];
  agg[n * D + t] = a;
}

// ---------------------------------------------------------------------------
// Weight pre-transpose: wT[j][o] for concatenated [rel ; root]
// ---------------------------------------------------------------------------
__global__ void transw_kernel(const float* __restrict__ g0_rel, const float* __restrict__ g0_root,
                              const float* __restrict__ g_rel, const float* __restrict__ g_root,
                              float* __restrict__ wT) {
  int idx = blockIdx.x * 256 + threadIdx.x;
  if (idx < 128 * 128) {  // layer 0: K=128 (64 agg + 64 root)
    int j = idx >> 7, o = idx & 127;
    wT[idx] = (j < 64) ? g0_rel[o * 64 + j] : g0_root[o * 64 + (j - 64)];
  }
  if (idx < 7 * 256 * 128) {  // layers 1..7: K=256
    int l = idx / (256 * 128);
    int r = idx % (256 * 128);
    int j = r >> 7, o = r & 127;
    wT[128 * 128 + idx] = (j < 128) ? g_rel[(l * 128 + o) * 128 + j]
                                    : g_root[(l * 128 + o) * 128 + (j - 128)];
  }
}

// out[n][o] = relu( sum_j A1[n][j]*wT[j][o](j<KA) + A2[n][j]*wT[KA+j][o] + bias[o] )
__global__ __launch_bounds__(256) void gemm_kernel(
    const float* __restrict__ A1, const float* __restrict__ A2,
    int KA, int KH,
    const float* __restrict__ wT, const float* __restrict__ bias,
    float* __restrict__ out) {
  __shared__ float as[256 * 20];  // [j][m], stride 20 keeps float4 aligned, spreads banks
  const int n0 = blockIdx.x * 16;
  const int tid = threadIdx.x;
  for (int idx = tid; idx < 16 * KA; idx += 256) {
    int m = idx / KA, j = idx % KA;
    as[j * 20 + m] = A1[(n0 + m) * KA + j];
  }
  for (int idx = tid; idx < 16 * KH; idx += 256) {
    int m = idx / KH, j = idx % KH;
    as[(KA + j) * 20 + m] = A2[(n0 + m) * KH + j];
  }
  __syncthreads();
  const int o = tid & 63;
  const int wv = tid >> 6;
  const int m0 = wv * 4;
  const int K = KA + KH;
  float a0[4] = {0, 0, 0, 0}, a1[4] = {0, 0, 0, 0};
  for (int j = 0; j < K; j++) {
    const float4 av = *(const float4*)&as[j * 20 + m0];
    float w0 = wT[j * 128 + o];
    float w1 = wT[j * 128 + o + 64];
    a0[0] += av.x * w0; a1[0] += av.x * w1;
    a0[1] += av.y * w0; a1[1] += av.y * w1;
    a0[2] += av.z * w0; a1[2] += av.z * w1;
    a0[3] += av.w * w0; a1[3] += av.w * w1;
  }
  float b0 = bias[o], b1 = bias[o + 64];
#pragma unroll
  for (int mm = 0; mm < 4; mm++) {
    out[(n0 + m0 + mm) * 128 + o] = fmaxf(a0[mm] + b0, 0.f);
    out[(n0 + m0 + mm) * 128 + o + 64] = fmaxf(a1[mm] + b1, 0.f);
  }
}

// ---------------------------------------------------------------------------
// Graph mean-pool (scatter) + MLP head + log_softmax
// ---------------------------------------------------------------------------
__global__ void pool_kernel(const float* __restrict__ h, const int* __restrict__ batch,
                            float* __restrict__ psum, int* __restrict__ pcnt) {
  int idx = blockIdx.x * 256 + threadIdx.x;
  int n = idx >> 7, t = idx & 127;
  int g = batch[n];
  atomicAdd(&psum[g * 128 + t], h[n * 128 + t]);
  if (t == 0) atomicAdd(&pcnt[g], 1);
}

__global__ __launch_bounds__(128) void mlp_kernel(
    const float* __restrict__ psum, const int* __restrict__ pcnt,
    const float* __restrict__ lin_w, const float* __restrict__ lin_b,
    const float* __restrict__ out_w, const float* __restrict__ out_b,
    float* __restrict__ out) {
  const int g = blockIdx.x;
  const int t = threadIdx.x;
  __shared__ float hs[128];
  __shared__ float lg[2];
  float c = (float)max(pcnt[g], 1);
  hs[t] = psum[g * 128 + t] / c;
  __syncthreads();
  for (int l = 0; l < 3; l++) {
    float acc = lin_b[l * 128 + t];
    for (int j = 0; j < 128; j++) acc += hs[j] * lin_w[(l * 128 + t) * 128 + j];
    __syncthreads();
    hs[t] = fmaxf(acc, 0.f);
    __syncthreads();
  }
  if (t < 2) {
    float acc = out_b[t];
    for (int j = 0; j < 128; j++) acc += hs[j] * out_w[t * 128 + j];
    lg[t] = acc;
  }
  __syncthreads();
  if (t < 2) {
    float m = fmaxf(lg[0], lg[1]);
    float lse = m + logf(expf(lg[0] - m) + expf(lg[1] - m));
    out[g * 2 + t] = lg[t] - lse;
  }
}

// ---------------------------------------------------------------------------
extern "C" void kernel_launch(void* const* d_in, const int* in_sizes, int n_in,
                              void* d_out, int out_size, void* d_ws, size_t ws_size,
                              hipStream_t stream) {
  const float* x       = (const float*)d_in[0];
  const int*   edge    = (const int*)d_in[1];
  const int*   batch   = (const int*)d_in[2];
  const float* cw0     = (const float*)d_in[3];
  const float* cb0     = (const float*)d_in[4];
  const float* cw_mid  = (const float*)d_in[5];
  const float* cb_mid  = (const float*)d_in[6];
  const float* cw_last = (const float*)d_in[7];
  const float* cb_last = (const float*)d_in[8];
  const float* enc_w   = (const float*)d_in[9];
  const float* enc_b   = (const float*)d_in[10];
  const float* g0_rel_w  = (const float*)d_in[11];
  const float* g0_rel_b  = (const float*)d_in[12];
  const float* g0_root_w = (const float*)d_in[13];
  const float* g_rel_w   = (const float*)d_in[14];
  const float* g_rel_b   = (const float*)d_in[15];
  const float* g_root_w  = (const float*)d_in[16];
  const float* lin_w     = (const float*)d_in[17];
  const float* lin_b     = (const float*)d_in[18];
  const float* out_w     = (const float*)d_in[19];
  const float* out_b     = (const float*)d_in[20];
  float* out = (float*)d_out;

  const int* esrc = edge;
  const int* edst = edge + E_EDGES;

  char* ws = (char*)d_ws;
  size_t off = 0;
  auto alloc = [&](size_t bytes) {
    void* p = ws + off;
    off += (bytes + 255) & ~size_t(255);
    return p;
  };
  float* henc = (float*)alloc((size_t)N_NODES * 64 * 4);
  float* hA   = (float*)alloc((size_t)N_NODES * 128 * 4);
  float* hB   = (float*)alloc((size_t)N_NODES * 128 * 4);
  float* agg  = (float*)alloc((size_t)N_NODES * 128 * 4);
  float* wT   = (float*)alloc((size_t)(128 * 128 + 7 * 256 * 128) * 4);
  float* psum = (float*)alloc((size_t)G * 128 * 4);
  int* cnt  = (int*)alloc((size_t)N_NODES * 4);
  int* rp   = (int*)alloc((size_t)(N_NODES + 1) * 4);
  int* cur  = (int*)alloc((size_t)N_NODES * 4);
  int* csr  = (int*)alloc((size_t)E_EDGES * 4);
  int* pcnt = (int*)alloc((size_t)G * 4);

  hipMemsetAsync(cnt, 0, (size_t)N_NODES * 4, stream);
  hipMemsetAsync(cur, 0, (size_t)N_NODES * 4, stream);
  hipMemsetAsync(psum, 0, (size_t)G * 128 * 4, stream);
  hipMemsetAsync(pcnt, 0, (size_t)G * 4, stream);

  conv_encode_kernel<<<N_NODES, 256, 0, stream>>>(x, cw0, cb0, cw_mid, cb_mid,
                                                  cw_last, cb_last, enc_w, enc_b, henc);
  hist_kernel<<<E_EDGES / 256, 256, 0, stream>>>(edst, cnt);
  scan_kernel<<<1, 256, 0, stream>>>(cnt, rp);
  fill_kernel<<<E_EDGES / 256, 256, 0, stream>>>(esrc, edst, rp, cur, csr);
  transw_kernel<<<(7 * 256 * 128) / 256, 256, 0, stream>>>(g0_rel_w, g0_root_w,
                                                           g_rel_w, g_root_w, wT);

  // layer 0 (F=64 -> H=128)
  gather_kernel<<<N_NODES, 64, 0, stream>>>(henc, csr, rp, agg, 64);
  gemm_kernel<<<N_NODES / 16, 256, 0, stream>>>(agg, henc, 64, 64, wT, g0_rel_b, hA);

  float* hprev = hA;
  float* hnext = hB;
  for (int l = 0; l < 7; l++) {
    gather_kernel<<<N_NODES, 128, 0, stream>>>(hprev, csr, rp, agg, 128);
    gemm_kernel<<<N_NODES / 16, 256, 0, stream>>>(agg, hprev, 128, 128,
        wT + 128 * 128 + l * 256 * 128, g_rel_b + l * 128, hnext);
    float* tmp = hprev; hprev = hnext; hnext = tmp;
  }

  pool_kernel<<<(N_NODES * 128) / 256, 256, 0, stream>>>(hprev, batch, psum, pcnt);
  mlp_kernel<<<G, 128, 0, stream>>>(psum, pcnt, lin_w, lin_b, out_w, out_b, out);
}

// Round 3
// 607.825 us; speedup vs baseline: 2.5805x; 2.5805x over previous
//
#include <hip/hip_runtime.h>
#include <hip/hip_bf16.h>

#define DEV_INLINE __device__ __forceinline__

typedef _Float16 f16;
typedef _Float16 f16x8 __attribute__((ext_vector_type(8)));
typedef float f32x16 __attribute__((ext_vector_type(16)));
typedef float f32x4 __attribute__((ext_vector_type(4)));

constexpr int N_NODES = 8192;
constexpr int G = 128;
constexpr int E_EDGES = 262144;

// ---------------------------------------------------------------------------
// LDS layout for the fused conv block (2 nodes/block).
// Activations: fp16, [node][parity][row][128B], row = halfpos+1 (1 guard row
// top/bottom, zeroed), 16B slots XOR-swizzled by row&7 for conflict-free
// ds_read_b128 / epilogue writes.
// ---------------------------------------------------------------------------
struct alignas(16) ConvLDS {
  union {
    char act1[2][2][66][128];              // L1 out (L2 in): 64 hr/par + guards
    struct {
      char act3[2][2][18][128];            // L3 out
      char act4[2][2][10][128];            // L4 out
      float act5[16][68];                  // L5 out, f32, padded stride
      float pooled[2][256];
      float encred[2][2][64];
    } tail;
  } A;
  char act2[2][2][34][128];                // L2 out
  float xs[2][264];                        // x staging, +3 guard each side
};

// one mid conv layer (K=64, KS=5, PAD=2) via mfma_f32_32x32x16_f16
// M = positions (2 nodes), N = 64 out-channels (2 tiles), D col = channel.
template<int MT, int LOG_PN, int IN_PS, int OUT_PS>
DEV_INLINE void conv_mfma(const f16* __restrict__ wb, const float* __restrict__ bias,
                          char* inb, char* outb, int w, int l) {
  const int nt = w & 1;
  const int o_lane = nt * 32 + (l & 31);
  const int khalf = l >> 5;  // 0/1: which 8 of the 16-k slice
  if ((w >> 1) < MT) {
    f16x8 wf[5][4];
#pragma unroll
    for (int k = 0; k < 5; k++)
#pragma unroll
      for (int s = 0; s < 4; s++)
        wf[k][s] = *(const f16x8*)&wb[(k * 64 + o_lane) * 64 + s * 16 + khalf * 8];
    const float bv = bias[o_lane];
    for (int mt = (w >> 1); mt < MT; mt += 2) {
      const int m = mt * 32 + (l & 31);
      const int node = m >> LOG_PN;
      const int p = m & ((1 << LOG_PN) - 1);
      f32x16 acc = {0,0,0,0,0,0,0,0,0,0,0,0,0,0,0,0};
#pragma unroll
      for (int k = 0; k < 5; k++) {
        const int d = k - 2;
        const int par = d & 1;
        const int row = p + (d >> 1) + 1;  // +1 guard offset
        const char* rb = inb + ((node * 2 + par) * IN_PS + row) * 128;
        const int fx = row & 7;
#pragma unroll
        for (int s = 0; s < 4; s++) {
          const int c8 = 2 * s + khalf;
          f16x8 af = *(const f16x8*)(rb + ((c8 ^ fx) << 4));
          acc = __builtin_amdgcn_mfma_f32_32x32x16_f16(af, wf[k][s], acc, 0, 0, 0);
        }
      }
      // D: col = l&31 (channel), row = (r&3)+8*(r>>2)+4*khalf (position)
#pragma unroll
      for (int r = 0; r < 16; r++) {
        const int rowD = (r & 3) + 8 * (r >> 2) + 4 * khalf;
        const int mo = mt * 32 + rowD;
        const int node_o = mo >> LOG_PN;
        const int po = mo & ((1 << LOG_PN) - 1);
        const int orow = (po >> 1) + 1;
        char* a = outb + ((node_o * 2 + (po & 1)) * OUT_PS + orow) * 128
                  + (((o_lane >> 3) ^ (orow & 7)) << 4) + (o_lane & 7) * 2;
        *(f16*)a = (f16)fmaxf(acc[r] + bv, 0.f);
      }
    }
  }
}

__global__ __launch_bounds__(256) void conv_encode_kernel(
    const float* __restrict__ x,
    const float* __restrict__ cw0, const float* __restrict__ cb0,
    const f16* __restrict__ wbmid, const float* __restrict__ cb_mid,
    const f16* __restrict__ wb5, const float* __restrict__ cb_last,
    const float* __restrict__ enc_w, const float* __restrict__ enc_b,
    float* __restrict__ henc) {
  __shared__ ConvLDS lds;
  const int tid = threadIdx.x;
  const int w = tid >> 6, l = tid & 63;
  const int n0 = blockIdx.x * 2;

  // zero act1 + act2 (guards must be 0; data rows get overwritten)
  {
    int4* z = (int4*)&lds;
    for (int i = tid; i < 51200 / 16; i += 256) z[i] = make_int4(0, 0, 0, 0);
  }
  // stage x (f32) with zero guards
  for (int idx = tid; idx < 512; idx += 256) {
    int node = idx >> 8, j = idx & 255;
    lds.xs[node][3 + j] = x[(size_t)(n0 + node) * 256 + j];
  }
  if (tid < 16) {
    int node = tid >> 3, s = tid & 7;
    int slot = (s < 3) ? s : (256 + s);  // 0,1,2,259..263
    lds.xs[node][slot] = 0.f;
  }
  __syncthreads();

  // ---- L1 (VALU): 1ch K=7 s2 p3, 256 -> 64ch x 128pos ----
  {
    const int o = tid & 63;
    const int half = (tid >> 6) & 1;
    const int node = tid >> 7;
    float w0r[7];
#pragma unroll
    for (int k = 0; k < 7; k++) w0r[k] = cw0[o * 7 + k];
    const float b0 = cb0[o];
    for (int i = 0; i < 64; i++) {
      const int p = half * 64 + i;
      const float* xp = &lds.xs[node][2 * p];  // x index 2p+k-3, +3 offset
      float s = b0;
#pragma unroll
      for (int k = 0; k < 7; k++) s += w0r[k] * xp[k];
      const int orow = (p >> 1) + 1;
      char* a = (char*)lds.A.act1 + ((node * 2 + (p & 1)) * 66 + orow) * 128
                + (((o >> 3) ^ (orow & 7)) << 4) + (o & 7) * 2;
      *(f16*)a = (f16)fmaxf(s, 0.f);
    }
  }
  __syncthreads();

  // ---- L2 (MFMA): 64x128 -> 64x64 ----
  conv_mfma<4, 6, 66, 34>(wbmid, cb_mid, (char*)lds.A.act1, (char*)lds.act2, w, l);
  __syncthreads();
  // act1 dead: zero tail region (act3/act4 guards)
  {
    int4* z = (int4*)&lds.A.tail;
    for (int i = tid; i < 21760 / 16; i += 256) z[i] = make_int4(0, 0, 0, 0);
  }
  __syncthreads();
  // ---- L3: 64x64 -> 64x32 ----
  conv_mfma<2, 5, 34, 18>(wbmid + 5 * 64 * 64, cb_mid + 64,
                          (char*)lds.act2, (char*)lds.A.tail.act3, w, l);
  __syncthreads();
  // ---- L4: 64x32 -> 64x16 ----
  conv_mfma<1, 4, 18, 10>(wbmid + 2 * 5 * 64 * 64, cb_mid + 128,
                          (char*)lds.A.tail.act3, (char*)lds.A.tail.act4, w, l);
  __syncthreads();

  // ---- L5 (MFMA 16x16x32): 64x16 -> 64x8, KS=3 PAD=1, M=16 pos (2 nodes) ----
  {
    const int o5 = w * 16 + (l & 15);  // wave = N-tile of 16 channels
    const int kq = l >> 4;             // 0..3: which 8 of the 32-k slice
    f16x8 wf5[3][2];
#pragma unroll
    for (int k = 0; k < 3; k++)
#pragma unroll
      for (int s = 0; s < 2; s++)
        wf5[k][s] = *(const f16x8*)&wb5[(k * 64 + o5) * 64 + s * 32 + kq * 8];
    const float b5 = cb_last[o5];
    f32x4 acc5 = {0, 0, 0, 0};
    const int m5 = l & 15, nd5 = m5 >> 3, p5 = m5 & 7;
#pragma unroll
    for (int k = 0; k < 3; k++) {
      const int d = k - 1;
      const int par = d & 1;
      const int row = p5 + (d >> 1) + 1;
      const char* rb = (char*)lds.A.tail.act4 + ((nd5 * 2 + par) * 10 + row) * 128;
      const int fx = row & 7;
#pragma unroll
      for (int s = 0; s < 2; s++) {
        const int c8 = 4 * s + kq;
        f16x8 af = *(const f16x8*)(rb + ((c8 ^ fx) << 4));
        acc5 = __builtin_amdgcn_mfma_f32_16x16x32_f16(af, wf5[k][s], acc5, 0, 0, 0);
      }
    }
    // D: col=l&15 (channel o5), row=kq*4+r (position over 2 nodes)
#pragma unroll
    for (int r = 0; r < 4; r++) {
      const int rowD = kq * 4 + r;
      const int ndo = rowD >> 3, po = rowD & 7;
      lds.A.tail.act5[ndo * 8 + po][o5] = fmaxf(acc5[r] + b5, 0.f);
    }
  }
  __syncthreads();

  // ---- avg-pool w3 s2 p1 over 8 pos -> 4; j = c*4+q ----
  for (int jj = tid; jj < 512; jj += 256) {
    int node = jj >> 8, j = jj & 255;
    int c = j >> 2, q = j & 3;
    const float* a5 = &lds.A.tail.act5[node * 8][0];
    float v = a5[(2 * q) * 68 + c] + a5[(2 * q + 1) * 68 + c];
    if (q > 0) v += a5[(2 * q - 1) * 68 + c];
    lds.A.tail.pooled[node][j] = v * (1.f / 3.f);
  }
  __syncthreads();

  // ---- encoder: henc[o] = pooled . enc_w[o,:] + enc_b[o] (no relu) ----
  {
    const int node = tid >> 7, tt = tid & 127;
    const int o = tt & 63, jg = tt >> 6;
    float acc = 0.f;
    const float4* ew = (const float4*)&enc_w[o * 256 + jg * 128];
    const float4* pj = (const float4*)&lds.A.tail.pooled[node][jg * 128];
#pragma unroll 4
    for (int j4 = 0; j4 < 32; j4++) {
      float4 a = ew[j4], b = pj[j4];
      acc += a.x * b.x + a.y * b.y + a.z * b.z + a.w * b.w;
    }
    lds.A.tail.encred[node][jg][o] = acc;
  }
  __syncthreads();
  if (tid < 128) {
    int node = tid >> 6, o = tid & 63;
    henc[(size_t)(n0 + node) * 64 + o] =
        lds.A.tail.encred[node][0][o] + lds.A.tail.encred[node][1][o] + enc_b[o];
  }
}

// ---------------------------------------------------------------------------
// conv-weight prep: fp32 (O,I,K) -> fp16 [layer][k][o][c]
// ---------------------------------------------------------------------------
__global__ void wprep_kernel(const float* __restrict__ cw_mid, const float* __restrict__ cw_last,
                             f16* __restrict__ wbmid, f16* __restrict__ wb5) {
  int idx = blockIdx.x * 256 + threadIdx.x;
  if (idx < 3 * 5 * 64 * 64) {
    int lay = idx / (5 * 64 * 64);
    int rem = idx % (5 * 64 * 64);
    int k = rem / 4096;
    int o = (rem >> 6) & 63;
    int c = rem & 63;
    wbmid[idx] = (f16)cw_mid[((lay * 64 + o) * 64 + c) * 5 + k];
  } else {
    int i2 = idx - 3 * 5 * 64 * 64;
    if (i2 < 3 * 64 * 64) {
      int k = i2 / 4096;
      int o = (i2 >> 6) & 63;
      int c = i2 & 63;
      wb5[i2] = (f16)cw_last[(o * 64 + c) * 3 + k];
    }
  }
}

// ---------------------------------------------------------------------------
// GNN phase (unchanged, fp32)
// ---------------------------------------------------------------------------
__global__ void hist_kernel(const int* __restrict__ dst, int* __restrict__ cnt) {
  int e = blockIdx.x * 256 + threadIdx.x;
  atomicAdd(&cnt[dst[e]], 1);
}

__global__ void scan_kernel(const int* __restrict__ cnt, int* __restrict__ rp) {
  __shared__ int part[256];
  int t = threadIdx.x;
  int base = t * 32;
  int local[32];
  int s = 0;
#pragma unroll
  for (int i = 0; i < 32; i++) { local[i] = cnt[base + i]; s += local[i]; }
  part[t] = s;
  __syncthreads();
  for (int off = 1; off < 256; off <<= 1) {
    int v = (t >= off) ? part[t - off] : 0;
    __syncthreads();
    part[t] += v;
    __syncthreads();
  }
  int run = part[t] - s;
#pragma unroll
  for (int i = 0; i < 32; i++) { rp[base + i] = run; run += local[i]; }
  if (t == 255) rp[N_NODES] = run;
}

__global__ void fill_kernel(const int* __restrict__ src, const int* __restrict__ dst,
                            const int* __restrict__ rp, int* __restrict__ cur,
                            int* __restrict__ csr) {
  int e = blockIdx.x * 256 + threadIdx.x;
  int r = dst[e];
  int p = atomicAdd(&cur[r], 1);
  csr[rp[r] + p] = src[e];
}

__global__ void gather_kernel(const float* __restrict__ h, const int* __restrict__ csr,
                              const int* __restrict__ rp, float* __restrict__ agg, int D) {
  int n = blockIdx.x;
  int t = threadIdx.x;
  int s = rp[n], e = rp[n + 1];
  float a = 0.f;
  for (int i = s; i < e; i++) a += h[csr[i] * D + t];
  agg[n * D + t] = a;
}

__global__ void transw_kernel(const float* __restrict__ g0_rel, const float* __restrict__ g0_root,
                              const float* __restrict__ g_rel, const float* __restrict__ g_root,
                              float* __restrict__ wT) {
  int idx = blockIdx.x * 256 + threadIdx.x;
  if (idx < 128 * 128) {
    int j = idx >> 7, o = idx & 127;
    wT[idx] = (j < 64) ? g0_rel[o * 64 + j] : g0_root[o * 64 + (j - 64)];
  }
  if (idx < 7 * 256 * 128) {
    int lsel = idx / (256 * 128);
    int r = idx % (256 * 128);
    int j = r >> 7, o = r & 127;
    wT[128 * 128 + idx] = (j < 128) ? g_rel[(lsel * 128 + o) * 128 + j]
                                    : g_root[(lsel * 128 + o) * 128 + (j - 128)];
  }
}

__global__ __launch_bounds__(256) void gemm_kernel(
    const float* __restrict__ A1, const float* __restrict__ A2,
    int KA, int KH,
    const float* __restrict__ wT, const float* __restrict__ bias,
    float* __restrict__ out) {
  __shared__ float as[256 * 20];
  const int n0 = blockIdx.x * 16;
  const int tid = threadIdx.x;
  for (int idx = tid; idx < 16 * KA; idx += 256) {
    int m = idx / KA, j = idx % KA;
    as[j * 20 + m] = A1[(n0 + m) * KA + j];
  }
  for (int idx = tid; idx < 16 * KH; idx += 256) {
    int m = idx / KH, j = idx % KH;
    as[(KA + j) * 20 + m] = A2[(n0 + m) * KH + j];
  }
  __syncthreads();
  const int o = tid & 63;
  const int wv = tid >> 6;
  const int m0 = wv * 4;
  const int K = KA + KH;
  float a0[4] = {0, 0, 0, 0}, a1[4] = {0, 0, 0, 0};
  for (int j = 0; j < K; j++) {
    const float4 av = *(const float4*)&as[j * 20 + m0];
    float w0 = wT[j * 128 + o];
    float w1 = wT[j * 128 + o + 64];
    a0[0] += av.x * w0; a1[0] += av.x * w1;
    a0[1] += av.y * w0; a1[1] += av.y * w1;
    a0[2] += av.z * w0; a1[2] += av.z * w1;
    a0[3] += av.w * w0; a1[3] += av.w * w1;
  }
  float b0 = bias[o], b1 = bias[o + 64];
#pragma unroll
  for (int mm = 0; mm < 4; mm++) {
    out[(n0 + m0 + mm) * 128 + o] = fmaxf(a0[mm] + b0, 0.f);
    out[(n0 + m0 + mm) * 128 + o + 64] = fmaxf(a1[mm] + b1, 0.f);
  }
}

__global__ void pool_kernel(const float* __restrict__ h, const int* __restrict__ batch,
                            float* __restrict__ psum, int* __restrict__ pcnt) {
  int idx = blockIdx.x * 256 + threadIdx.x;
  int n = idx >> 7, t = idx & 127;
  int g = batch[n];
  atomicAdd(&psum[g * 128 + t], h[n * 128 + t]);
  if (t == 0) atomicAdd(&pcnt[g], 1);
}

__global__ __launch_bounds__(128) void mlp_kernel(
    const float* __restrict__ psum, const int* __restrict__ pcnt,
    const float* __restrict__ lin_w, const float* __restrict__ lin_b,
    const float* __restrict__ out_w, const float* __restrict__ out_b,
    float* __restrict__ out) {
  const int g = blockIdx.x;
  const int t = threadIdx.x;
  __shared__ float hs[128];
  __shared__ float lg[2];
  float c = (float)max(pcnt[g], 1);
  hs[t] = psum[g * 128 + t] / c;
  __syncthreads();
  for (int lsel = 0; lsel < 3; lsel++) {
    float acc = lin_b[lsel * 128 + t];
    for (int j = 0; j < 128; j++) acc += hs[j] * lin_w[(lsel * 128 + t) * 128 + j];
    __syncthreads();
    hs[t] = fmaxf(acc, 0.f);
    __syncthreads();
  }
  if (t < 2) {
    float acc = out_b[t];
    for (int j = 0; j < 128; j++) acc += hs[j] * out_w[t * 128 + j];
    lg[t] = acc;
  }
  __syncthreads();
  if (t < 2) {
    float m = fmaxf(lg[0], lg[1]);
    float lse = m + logf(expf(lg[0] - m) + expf(lg[1] - m));
    out[g * 2 + t] = lg[t] - lse;
  }
}

// ---------------------------------------------------------------------------
extern "C" void kernel_launch(void* const* d_in, const int* in_sizes, int n_in,
                              void* d_out, int out_size, void* d_ws, size_t ws_size,
                              hipStream_t stream) {
  const float* x       = (const float*)d_in[0];
  const int*   edge    = (const int*)d_in[1];
  const int*   batch   = (const int*)d_in[2];
  const float* cw0     = (const float*)d_in[3];
  const float* cb0     = (const float*)d_in[4];
  const float* cw_mid  = (const float*)d_in[5];
  const float* cb_mid  = (const float*)d_in[6];
  const float* cw_last = (const float*)d_in[7];
  const float* cb_last = (const float*)d_in[8];
  const float* enc_w   = (const float*)d_in[9];
  const float* enc_b   = (const float*)d_in[10];
  const float* g0_rel_w  = (const float*)d_in[11];
  const float* g0_rel_b  = (const float*)d_in[12];
  const float* g0_root_w = (const float*)d_in[13];
  const float* g_rel_w   = (const float*)d_in[14];
  const float* g_rel_b   = (const float*)d_in[15];
  const float* g_root_w  = (const float*)d_in[16];
  const float* lin_w     = (const float*)d_in[17];
  const float* lin_b     = (const float*)d_in[18];
  const float* out_w     = (const float*)d_in[19];
  const float* out_b     = (const float*)d_in[20];
  float* out = (float*)d_out;

  const int* esrc = edge;
  const int* edst = edge + E_EDGES;

  char* ws = (char*)d_ws;
  size_t off = 0;
  auto alloc = [&](size_t bytes) {
    void* p = ws + off;
    off += (bytes + 255) & ~size_t(255);
    return p;
  };
  float* henc = (float*)alloc((size_t)N_NODES * 64 * 4);
  float* hA   = (float*)alloc((size_t)N_NODES * 128 * 4);
  float* hB   = (float*)alloc((size_t)N_NODES * 128 * 4);
  float* agg  = (float*)alloc((size_t)N_NODES * 128 * 4);
  float* wT   = (float*)alloc((size_t)(128 * 128 + 7 * 256 * 128) * 4);
  float* psum = (float*)alloc((size_t)G * 128 * 4);
  int* cnt  = (int*)alloc((size_t)N_NODES * 4);
  int* rp   = (int*)alloc((size_t)(N_NODES + 1) * 4);
  int* cur  = (int*)alloc((size_t)N_NODES * 4);
  int* csr  = (int*)alloc((size_t)E_EDGES * 4);
  int* pcnt = (int*)alloc((size_t)G * 4);
  f16* wbmid = (f16*)alloc((size_t)3 * 5 * 64 * 64 * 2);
  f16* wb5   = (f16*)alloc((size_t)3 * 64 * 64 * 2);

  hipMemsetAsync(cnt, 0, (size_t)N_NODES * 4, stream);
  hipMemsetAsync(cur, 0, (size_t)N_NODES * 4, stream);
  hipMemsetAsync(psum, 0, (size_t)G * 128 * 4, stream);
  hipMemsetAsync(pcnt, 0, (size_t)G * 4, stream);

  wprep_kernel<<<288, 256, 0, stream>>>(cw_mid, cw_last, wbmid, wb5);
  conv_encode_kernel<<<N_NODES / 2, 256, 0, stream>>>(
      x, cw0, cb0, wbmid, cb_mid, wb5, cb_last, enc_w, enc_b, henc);

  hist_kernel<<<E_EDGES / 256, 256, 0, stream>>>(edst, cnt);
  scan_kernel<<<1, 256, 0, stream>>>(cnt, rp);
  fill_kernel<<<E_EDGES / 256, 256, 0, stream>>>(esrc, edst, rp, cur, csr);
  transw_kernel<<<(7 * 256 * 128) / 256, 256, 0, stream>>>(g0_rel_w, g0_root_w,
                                                           g_rel_w, g_root_w, wT);

  gather_kernel<<<N_NODES, 64, 0, stream>>>(henc, csr, rp, agg, 64);
  gemm_kernel<<<N_NODES / 16, 256, 0, stream>>>(agg, henc, 64, 64, wT, g0_rel_b, hA);

  float* hprev = hA;
  float* hnext = hB;
  for (int lsel = 0; lsel < 7; lsel++) {
    gather_kernel<<<N_NODES, 128, 0, stream>>>(hprev, csr, rp, agg, 128);
    gemm_kernel<<<N_NODES / 16, 256, 0, stream>>>(agg, hprev, 128, 128,
        wT + 128 * 128 + lsel * 256 * 128, g_rel_b + lsel * 128, hnext);
    float* tmp = hprev; hprev = hnext; hnext = tmp;
  }

  pool_kernel<<<(N_NODES * 128) / 256, 256, 0, stream>>>(hprev, batch, psum, pcnt);
  mlp_kernel<<<G, 128, 0, stream>>>(psum, pcnt, lin_w, lin_b, out_w, out_b, out);
}

// Round 6
// 538.185 us; speedup vs baseline: 2.9144x; 1.1294x over previous
//
#include <hip/hip_runtime.h>
#include <hip/hip_bf16.h>

#define DEV_INLINE __device__ __forceinline__

typedef _Float16 f16;
typedef _Float16 f16x8 __attribute__((ext_vector_type(8)));
typedef __bf16 bf16;
typedef __bf16 bf16x8 __attribute__((ext_vector_type(8)));
typedef float f32x16 __attribute__((ext_vector_type(16)));
typedef float f32x4 __attribute__((ext_vector_type(4)));

constexpr int N_NODES = 8192;
constexpr int G = 128;
constexpr int E_EDGES = 262144;

// ---------------------------------------------------------------------------
// Fused conv stack (fp16 MFMA) — identical to round-3 passing version
// ---------------------------------------------------------------------------
struct alignas(16) ConvLDS {
  union {
    char act1[2][2][66][128];
    struct {
      char act3[2][2][18][128];
      char act4[2][2][10][128];
      float act5[16][68];
      float pooled[2][256];
      float encred[2][2][64];
    } tail;
  } A;
  char act2[2][2][34][128];
  float xs[2][264];
};

template<int MT, int LOG_PN, int IN_PS, int OUT_PS>
DEV_INLINE void conv_mfma(const f16* __restrict__ wb, const float* __restrict__ bias,
                          char* inb, char* outb, int w, int l) {
  const int nt = w & 1;
  const int o_lane = nt * 32 + (l & 31);
  const int khalf = l >> 5;
  if ((w >> 1) < MT) {
    f16x8 wf[5][4];
#pragma unroll
    for (int k = 0; k < 5; k++)
#pragma unroll
      for (int s = 0; s < 4; s++)
        wf[k][s] = *(const f16x8*)&wb[(k * 64 + o_lane) * 64 + s * 16 + khalf * 8];
    const float bv = bias[o_lane];
    for (int mt = (w >> 1); mt < MT; mt += 2) {
      const int p = (mt * 32 + (l & 31)) & ((1 << LOG_PN) - 1);
      const int node = (mt * 32 + (l & 31)) >> LOG_PN;
      f32x16 acc = {0,0,0,0,0,0,0,0,0,0,0,0,0,0,0,0};
#pragma unroll
      for (int k = 0; k < 5; k++) {
        const int d = k - 2;
        const int par = d & 1;
        const int row = p + (d >> 1) + 1;
        const char* rb = inb + ((node * 2 + par) * IN_PS + row) * 128;
        const int fx = row & 7;
#pragma unroll
        for (int s = 0; s < 4; s++) {
          const int c8 = 2 * s + khalf;
          f16x8 af = *(const f16x8*)(rb + ((c8 ^ fx) << 4));
          acc = __builtin_amdgcn_mfma_f32_32x32x16_f16(af, wf[k][s], acc, 0, 0, 0);
        }
      }
#pragma unroll
      for (int r = 0; r < 16; r++) {
        const int rowD = (r & 3) + 8 * (r >> 2) + 4 * khalf;
        const int mo = mt * 32 + rowD;
        const int node_o = mo >> LOG_PN;
        const int po = mo & ((1 << LOG_PN) - 1);
        const int orow = (po >> 1) + 1;
        char* a = outb + ((node_o * 2 + (po & 1)) * OUT_PS + orow) * 128
                  + (((o_lane >> 3) ^ (orow & 7)) << 4) + (o_lane & 7) * 2;
        *(f16*)a = (f16)fmaxf(acc[r] + bv, 0.f);
      }
    }
  }
}

__global__ __launch_bounds__(256) void conv_encode_kernel(
    const float* __restrict__ x,
    const float* __restrict__ cw0, const float* __restrict__ cb0,
    const f16* __restrict__ wbmid, const float* __restrict__ cb_mid,
    const f16* __restrict__ wb5, const float* __restrict__ cb_last,
    const float* __restrict__ enc_w, const float* __restrict__ enc_b,
    float* __restrict__ henc) {
  __shared__ ConvLDS lds;
  const int tid = threadIdx.x;
  const int w = tid >> 6, l = tid & 63;
  const int n0 = blockIdx.x * 2;

  {
    int4* z = (int4*)&lds;
    for (int i = tid; i < 51200 / 16; i += 256) z[i] = make_int4(0, 0, 0, 0);
  }
  for (int idx = tid; idx < 512; idx += 256) {
    int node = idx >> 8, j = idx & 255;
    lds.xs[node][3 + j] = x[(size_t)(n0 + node) * 256 + j];
  }
  if (tid < 16) {
    int node = tid >> 3, s = tid & 7;
    int slot = (s < 3) ? s : (256 + s);
    lds.xs[node][slot] = 0.f;
  }
  __syncthreads();

  {
    const int o = tid & 63;
    const int half = (tid >> 6) & 1;
    const int node = tid >> 7;
    float w0r[7];
#pragma unroll
    for (int k = 0; k < 7; k++) w0r[k] = cw0[o * 7 + k];
    const float b0 = cb0[o];
    for (int i = 0; i < 64; i++) {
      const int p = half * 64 + i;
      const float* xp = &lds.xs[node][2 * p];
      float s = b0;
#pragma unroll
      for (int k = 0; k < 7; k++) s += w0r[k] * xp[k];
      const int orow = (p >> 1) + 1;
      char* a = (char*)lds.A.act1 + ((node * 2 + (p & 1)) * 66 + orow) * 128
                + (((o >> 3) ^ (orow & 7)) << 4) + (o & 7) * 2;
      *(f16*)a = (f16)fmaxf(s, 0.f);
    }
  }
  __syncthreads();

  conv_mfma<4, 6, 66, 34>(wbmid, cb_mid, (char*)lds.A.act1, (char*)lds.act2, w, l);
  __syncthreads();
  {
    int4* z = (int4*)&lds.A.tail;
    for (int i = tid; i < 21760 / 16; i += 256) z[i] = make_int4(0, 0, 0, 0);
  }
  __syncthreads();
  conv_mfma<2, 5, 34, 18>(wbmid + 5 * 64 * 64, cb_mid + 64,
                          (char*)lds.act2, (char*)lds.A.tail.act3, w, l);
  __syncthreads();
  conv_mfma<1, 4, 18, 10>(wbmid + 2 * 5 * 64 * 64, cb_mid + 128,
                          (char*)lds.A.tail.act3, (char*)lds.A.tail.act4, w, l);
  __syncthreads();

  {
    const int o5 = w * 16 + (l & 15);
    const int kq = l >> 4;
    f16x8 wf5[3][2];
#pragma unroll
    for (int k = 0; k < 3; k++)
#pragma unroll
      for (int s = 0; s < 2; s++)
        wf5[k][s] = *(const f16x8*)&wb5[(k * 64 + o5) * 64 + s * 32 + kq * 8];
    const float b5 = cb_last[o5];
    f32x4 acc5 = {0, 0, 0, 0};
    const int m5 = l & 15, nd5 = m5 >> 3, p5 = m5 & 7;
#pragma unroll
    for (int k = 0; k < 3; k++) {
      const int d = k - 1;
      const int par = d & 1;
      const int row = p5 + (d >> 1) + 1;
      const char* rb = (char*)lds.A.tail.act4 + ((nd5 * 2 + par) * 10 + row) * 128;
      const int fx = row & 7;
#pragma unroll
      for (int s = 0; s < 2; s++) {
        const int c8 = 4 * s + kq;
        f16x8 af = *(const f16x8*)(rb + ((c8 ^ fx) << 4));
        acc5 = __builtin_amdgcn_mfma_f32_16x16x32_f16(af, wf5[k][s], acc5, 0, 0, 0);
      }
    }
#pragma unroll
    for (int r = 0; r < 4; r++) {
      const int rowD = kq * 4 + r;
      const int ndo = rowD >> 3, po = rowD & 7;
      lds.A.tail.act5[ndo * 8 + po][o5] = fmaxf(acc5[r] + b5, 0.f);
    }
  }
  __syncthreads();

  for (int jj = tid; jj < 512; jj += 256) {
    int node = jj >> 8, j = jj & 255;
    int c = j >> 2, q = j & 3;
    const float* a5 = &lds.A.tail.act5[node * 8][0];
    float v = a5[(2 * q) * 68 + c] + a5[(2 * q + 1) * 68 + c];
    if (q > 0) v += a5[(2 * q - 1) * 68 + c];
    lds.A.tail.pooled[node][j] = v * (1.f / 3.f);
  }
  __syncthreads();

  {
    const int node = tid >> 7, tt = tid & 127;
    const int o = tt & 63, jg = tt >> 6;
    float acc = 0.f;
    const float4* ew = (const float4*)&enc_w[o * 256 + jg * 128];
    const float4* pj = (const float4*)&lds.A.tail.pooled[node][jg * 128];
#pragma unroll 4
    for (int j4 = 0; j4 < 32; j4++) {
      float4 a = ew[j4], b = pj[j4];
      acc += a.x * b.x + a.y * b.y + a.z * b.z + a.w * b.w;
    }
    lds.A.tail.encred[node][jg][o] = acc;
  }
  __syncthreads();
  if (tid < 128) {
    int node = tid >> 6, o = tid & 63;
    henc[(size_t)(n0 + node) * 64 + o] =
        lds.A.tail.encred[node][0][o] + lds.A.tail.encred[node][1][o] + enc_b[o];
  }
}

// ---------------------------------------------------------------------------
// conv-weight prep (unchanged)
// ---------------------------------------------------------------------------
__global__ void wprep_kernel(const float* __restrict__ cw_mid, const float* __restrict__ cw_last,
                             f16* __restrict__ wbmid, f16* __restrict__ wb5) {
  int idx = blockIdx.x * 256 + threadIdx.x;
  if (idx < 3 * 5 * 64 * 64) {
    int lay = idx / (5 * 64 * 64);
    int rem = idx % (5 * 64 * 64);
    int k = rem / 4096;
    int o = (rem >> 6) & 63;
    int c = rem & 63;
    wbmid[idx] = (f16)cw_mid[((lay * 64 + o) * 64 + c) * 5 + k];
  } else {
    int i2 = idx - 3 * 5 * 64 * 64;
    if (i2 < 3 * 64 * 64) {
      int k = i2 / 4096;
      int o = (i2 >> 6) & 63;
      int c = i2 & 63;
      wb5[i2] = (f16)cw_last[(o * 64 + c) * 3 + k];
    }
  }
}

// ---------------------------------------------------------------------------
// GNN weight prep: bf16 hi/lo planes, [o][k] with rel||root concat along k.
// Layer 0 at offset 0 (2 planes of 128*128); layers 1..7 after (2 planes of
// 128*256 each). bias TRUE f32.
// ---------------------------------------------------------------------------
__global__ void wprep_gnn(const float* __restrict__ g0_rel, const float* __restrict__ g0_root,
                          const float* __restrict__ g0_rel_b,
                          const float* __restrict__ g_rel, const float* __restrict__ g_root,
                          const float* __restrict__ g_rel_b,
                          bf16* __restrict__ wg, float* __restrict__ bg) {
  int idx = blockIdx.x * 256 + threadIdx.x;
  if (idx < 128 * 128) {
    int o = idx >> 7, k = idx & 127;
    float v = (k < 64) ? g0_rel[o * 64 + k] : g0_root[o * 64 + (k - 64)];
    bf16 h = (bf16)v;
    wg[idx] = h;
    wg[128 * 128 + idx] = (bf16)(v - (float)h);
  }
  if (idx < 7 * 128 * 256) {
    int lsel = idx / (128 * 256);
    int r = idx % (128 * 256);
    int o = r >> 8, k = r & 255;
    float v = (k < 128) ? g_rel[(lsel * 128 + o) * 128 + k]
                        : g_root[(lsel * 128 + o) * 128 + (k - 128)];
    bf16 h = (bf16)v;
    size_t base = 2 * 128 * 128 + (size_t)lsel * 2 * 128 * 256;
    wg[base + r] = h;
    wg[base + 128 * 256 + r] = (bf16)(v - (float)h);
  }
  if (idx < 8 * 128) {
    int lsel = idx >> 7, o = idx & 127;
    bg[idx] = (lsel == 0) ? g0_rel_b[o] : g_rel_b[(lsel - 1) * 128 + o];
  }
}

// ---------------------------------------------------------------------------
// CSR build (unchanged)
// ---------------------------------------------------------------------------
__global__ void hist_kernel(const int* __restrict__ dst, int* __restrict__ cnt) {
  int e = blockIdx.x * 256 + threadIdx.x;
  atomicAdd(&cnt[dst[e]], 1);
}

__global__ void scan_kernel(const int* __restrict__ cnt, int* __restrict__ rp) {
  __shared__ int part[256];
  int t = threadIdx.x;
  int base = t * 32;
  int local[32];
  int s = 0;
#pragma unroll
  for (int i = 0; i < 32; i++) { local[i] = cnt[base + i]; s += local[i]; }
  part[t] = s;
  __syncthreads();
  for (int off = 1; off < 256; off <<= 1) {
    int v = (t >= off) ? part[t - off] : 0;
    __syncthreads();
    part[t] += v;
    __syncthreads();
  }
  int run = part[t] - s;
#pragma unroll
  for (int i = 0; i < 32; i++) { rp[base + i] = run; run += local[i]; }
  if (t == 255) rp[N_NODES] = run;
}

__global__ void fill_kernel(const int* __restrict__ src, const int* __restrict__ dst,
                            const int* __restrict__ rp, int* __restrict__ cur,
                            int* __restrict__ csr) {
  int e = blockIdx.x * 256 + threadIdx.x;
  int r = dst[e];
  int p = atomicAdd(&cur[r], 1);
  csr[rp[r] + p] = src[e];
}

// ---------------------------------------------------------------------------
// f32 gather: agg[n] = sum_{nbr} h[nbr]
// ---------------------------------------------------------------------------
template<int D>
__global__ void gatherf(const float* __restrict__ h, const int* __restrict__ csr,
                        const int* __restrict__ rp, float* __restrict__ agg) {
  const int wid = threadIdx.x >> 6;
  const int lane = threadIdx.x & 63;
  int node, cl;
  if (D == 128) { node = blockIdx.x * 4 + wid; cl = lane; }
  else { node = blockIdx.x * 8 + wid * 2 + (lane >> 5); cl = lane & 31; }
  const int s = rp[node], e = rp[node + 1];
  float a0 = 0.f, a1 = 0.f;
  for (int i = s; i < e; i++) {
    const int m = csr[i];
    float2 v = *(const float2*)&h[(size_t)m * D + cl * 2];
    a0 += v.x;
    a1 += v.y;
  }
  *(float2*)&agg[(size_t)node * D + cl * 2] = make_float2(a0, a1);
}

// ---------------------------------------------------------------------------
// GNN layer GEMM, bf16 hi/lo split on BOTH operands (no range hazard):
// hout[64n x 128] = relu( [agg|hroot] @ W^T + b )
// acc += Ahi*Whi + Alo*Whi + Ahi*Wlo   (lo*lo dropped, ~2^-18 rel)
// ---------------------------------------------------------------------------
template<int K>
__global__ __launch_bounds__(256) void gnn_gemm_bf(
    const float* __restrict__ agg, const float* __restrict__ hroot,
    const bf16* __restrict__ wg, const float* __restrict__ bg,
    float* __restrict__ hout) {
  constexpr int F = K / 2;
  constexpr int ROWB = K * 2;                       // bytes per row per plane
  constexpr int KSTEPS = K / 16;
  __shared__ alignas(16) char smem[2][64 * K * 2];  // [hi/lo][row][k] bf16
  const int tid = threadIdx.x;
  const int l = tid & 63, w = tid >> 6;
  const int n0 = blockIdx.x * 64;

  // stage [agg | hroot], 4 threads/row, 16B slots, slot ^= row&7 (T2)
  {
    const int row = tid >> 2, p = tid & 3;
    constexpr int cpp = K / 32;
#pragma unroll
    for (int j = 0; j < cpp; j++) {
      const int slot = p * cpp + j;
      const int c0 = slot * 8;
      const float* src = (c0 < F) ? &agg[(size_t)(n0 + row) * F + c0]
                                  : &hroot[(size_t)(n0 + row) * F + (c0 - F)];
      float4 v0 = ((const float4*)src)[0];
      float4 v1 = ((const float4*)src)[1];
      float vv[8] = {v0.x, v0.y, v0.z, v0.w, v1.x, v1.y, v1.z, v1.w};
      bf16x8 hi8, lo8;
#pragma unroll
      for (int e = 0; e < 8; e++) {
        float v = vv[e];
        bf16 h = (bf16)v;
        hi8[e] = h;
        lo8[e] = (bf16)(v - (float)h);
      }
      const int off = row * ROWB + ((slot ^ (row & 7)) << 4);
      *(bf16x8*)(smem[0] + off) = hi8;
      *(bf16x8*)(smem[1] + off) = lo8;
    }
  }

  // B-frags: wave w owns out-channels [w*32, w*32+32); hi and lo planes
  const int ch = w * 32 + (l & 31);
  const int khalf = l >> 5;
  bf16x8 whi[KSTEPS], wlo[KSTEPS];
  const bf16* wrow = wg + (size_t)ch * K + khalf * 8;
#pragma unroll
  for (int ks = 0; ks < KSTEPS; ks++) {
    whi[ks] = *(const bf16x8*)&wrow[ks * 16];
    wlo[ks] = *(const bf16x8*)&wrow[128 * K + ks * 16];
  }
  const float bv = bg[ch];

  __syncthreads();

  const int row0 = l & 31;
  f32x16 acc0 = {0,0,0,0,0,0,0,0,0,0,0,0,0,0,0,0};
  f32x16 acc1 = {0,0,0,0,0,0,0,0,0,0,0,0,0,0,0,0};
#pragma unroll
  for (int ks = 0; ks < KSTEPS; ks++) {
    const int slot = ks * 2 + khalf;
    const int xr = (slot ^ (row0 & 7)) << 4;        // (row0+32)&7 == row0&7
    const int o0 = row0 * ROWB + xr;
    const int o1 = (row0 + 32) * ROWB + xr;
    bf16x8 ah0 = *(const bf16x8*)(smem[0] + o0);
    bf16x8 al0 = *(const bf16x8*)(smem[1] + o0);
    bf16x8 ah1 = *(const bf16x8*)(smem[0] + o1);
    bf16x8 al1 = *(const bf16x8*)(smem[1] + o1);
    acc0 = __builtin_amdgcn_mfma_f32_32x32x16_bf16(ah0, whi[ks], acc0, 0, 0, 0);
    acc0 = __builtin_amdgcn_mfma_f32_32x32x16_bf16(al0, whi[ks], acc0, 0, 0, 0);
    acc0 = __builtin_amdgcn_mfma_f32_32x32x16_bf16(ah0, wlo[ks], acc0, 0, 0, 0);
    acc1 = __builtin_amdgcn_mfma_f32_32x32x16_bf16(ah1, whi[ks], acc1, 0, 0, 0);
    acc1 = __builtin_amdgcn_mfma_f32_32x32x16_bf16(al1, whi[ks], acc1, 0, 0, 0);
    acc1 = __builtin_amdgcn_mfma_f32_32x32x16_bf16(ah1, wlo[ks], acc1, 0, 0, 0);
  }

#pragma unroll
  for (int r = 0; r < 16; r++) {
    const int nl = (r & 3) + 8 * (r >> 2) + 4 * khalf;
    hout[(size_t)(n0 + nl) * 128 + ch] = fmaxf(acc0[r] + bv, 0.f);
    hout[(size_t)(n0 + 32 + nl) * 128 + ch] = fmaxf(acc1[r] + bv, 0.f);
  }
}

// ---------------------------------------------------------------------------
// pool (f32) + MLP head
// ---------------------------------------------------------------------------
__global__ void poolf(const float* __restrict__ h, const int* __restrict__ batch,
                      float* __restrict__ psum, int* __restrict__ pcnt) {
  int idx = blockIdx.x * 256 + threadIdx.x;
  int n = idx >> 7, t = idx & 127;
  int g = batch[n];
  atomicAdd(&psum[g * 128 + t], h[(size_t)n * 128 + t]);
  if (t == 0) atomicAdd(&pcnt[g], 1);
}

__global__ __launch_bounds__(128) void mlp_kernel(
    const float* __restrict__ psum, const int* __restrict__ pcnt,
    const float* __restrict__ lin_w, const float* __restrict__ lin_b,
    const float* __restrict__ out_w, const float* __restrict__ out_b,
    float* __restrict__ out) {
  const int g = blockIdx.x;
  const int t = threadIdx.x;
  __shared__ float hs[128];
  __shared__ float lg[2];
  float c = (float)max(pcnt[g], 1);
  hs[t] = psum[g * 128 + t] / c;
  __syncthreads();
  for (int lsel = 0; lsel < 3; lsel++) {
    float acc = lin_b[lsel * 128 + t];
    for (int j = 0; j < 128; j++) acc += hs[j] * lin_w[(lsel * 128 + t) * 128 + j];
    __syncthreads();
    hs[t] = fmaxf(acc, 0.f);
    __syncthreads();
  }
  if (t < 2) {
    float acc = out_b[t];
    for (int j = 0; j < 128; j++) acc += hs[j] * out_w[t * 128 + j];
    lg[t] = acc;
  }
  __syncthreads();
  if (t < 2) {
    float m = fmaxf(lg[0], lg[1]);
    float lse = m + logf(expf(lg[0] - m) + expf(lg[1] - m));
    out[g * 2 + t] = lg[t] - lse;
  }
}

// ---------------------------------------------------------------------------
extern "C" void kernel_launch(void* const* d_in, const int* in_sizes, int n_in,
                              void* d_out, int out_size, void* d_ws, size_t ws_size,
                              hipStream_t stream) {
  const float* x       = (const float*)d_in[0];
  const int*   edge    = (const int*)d_in[1];
  const int*   batch   = (const int*)d_in[2];
  const float* cw0     = (const float*)d_in[3];
  const float* cb0     = (const float*)d_in[4];
  const float* cw_mid  = (const float*)d_in[5];
  const float* cb_mid  = (const float*)d_in[6];
  const float* cw_last = (const float*)d_in[7];
  const float* cb_last = (const float*)d_in[8];
  const float* enc_w   = (const float*)d_in[9];
  const float* enc_b   = (const float*)d_in[10];
  const float* g0_rel_w  = (const float*)d_in[11];
  const float* g0_rel_b  = (const float*)d_in[12];
  const float* g0_root_w = (const float*)d_in[13];
  const float* g_rel_w   = (const float*)d_in[14];
  const float* g_rel_b   = (const float*)d_in[15];
  const float* g_root_w  = (const float*)d_in[16];
  const float* lin_w     = (const float*)d_in[17];
  const float* lin_b     = (const float*)d_in[18];
  const float* out_w     = (const float*)d_in[19];
  const float* out_b     = (const float*)d_in[20];
  float* out = (float*)d_out;

  const int* esrc = edge;
  const int* edst = edge + E_EDGES;

  char* ws = (char*)d_ws;
  size_t off = 0;
  auto alloc = [&](size_t bytes) {
    void* p = ws + off;
    off += (bytes + 255) & ~size_t(255);
    return p;
  };
  float* henc = (float*)alloc((size_t)N_NODES * 64 * 4);
  float* hA   = (float*)alloc((size_t)N_NODES * 128 * 4);
  float* hB   = (float*)alloc((size_t)N_NODES * 128 * 4);
  float* agg  = (float*)alloc((size_t)N_NODES * 128 * 4);
  bf16* wg    = (bf16*)alloc((size_t)(128 * 128 + 7 * 128 * 256) * 2 * 2);  // hi+lo planes
  float* bg   = (float*)alloc((size_t)8 * 128 * 4);
  float* psum = (float*)alloc((size_t)G * 128 * 4);
  int* cnt  = (int*)alloc((size_t)N_NODES * 4);
  int* rp   = (int*)alloc((size_t)(N_NODES + 1) * 4);
  int* cur  = (int*)alloc((size_t)N_NODES * 4);
  int* csr  = (int*)alloc((size_t)E_EDGES * 4);
  int* pcnt = (int*)alloc((size_t)G * 4);
  f16* wbmid = (f16*)alloc((size_t)3 * 5 * 64 * 64 * 2);
  f16* wb5   = (f16*)alloc((size_t)3 * 64 * 64 * 2);

  hipMemsetAsync(cnt, 0, (size_t)N_NODES * 4, stream);
  hipMemsetAsync(cur, 0, (size_t)N_NODES * 4, stream);
  hipMemsetAsync(psum, 0, (size_t)G * 128 * 4, stream);
  hipMemsetAsync(pcnt, 0, (size_t)G * 4, stream);

  wprep_kernel<<<288, 256, 0, stream>>>(cw_mid, cw_last, wbmid, wb5);
  wprep_gnn<<<896, 256, 0, stream>>>(g0_rel_w, g0_root_w, g0_rel_b,
                                     g_rel_w, g_root_w, g_rel_b, wg, bg);
  conv_encode_kernel<<<N_NODES / 2, 256, 0, stream>>>(
      x, cw0, cb0, wbmid, cb_mid, wb5, cb_last, enc_w, enc_b, henc);

  hist_kernel<<<E_EDGES / 256, 256, 0, stream>>>(edst, cnt);
  scan_kernel<<<1, 256, 0, stream>>>(cnt, rp);
  fill_kernel<<<E_EDGES / 256, 256, 0, stream>>>(esrc, edst, rp, cur, csr);

  // layer 0 (K=128: 64 agg + 64 root)
  gatherf<64><<<N_NODES / 8, 256, 0, stream>>>(henc, csr, rp, agg);
  gnn_gemm_bf<128><<<N_NODES / 64, 256, 0, stream>>>(agg, henc, wg, bg, hA);

  float* hprev = hA;
  float* hnext = hB;
  for (int lsel = 0; lsel < 7; lsel++) {
    gatherf<128><<<N_NODES / 4, 256, 0, stream>>>(hprev, csr, rp, agg);
    gnn_gemm_bf<256><<<N_NODES / 64, 256, 0, stream>>>(
        agg, hprev, wg + 2 * 128 * 128 + (size_t)lsel * 2 * 128 * 256,
        bg + (lsel + 1) * 128, hnext);
    float* tmp = hprev; hprev = hnext; hnext = tmp;
  }

  poolf<<<(N_NODES * 128) / 256, 256, 0, stream>>>(hprev, batch, psum, pcnt);
  mlp_kernel<<<G, 128, 0, stream>>>(psum, pcnt, lin_w, lin_b, out_w, out_b, out);
}